// Round 9
// baseline (193.761 us; speedup 1.0000x reference)
//
#include <hip/hip_runtime.h>
#include <hip/hip_bf16.h>

// Problem: lstm_20169166422798
// x:(64,512,513) W_ih:(200,513) W_hh:(200,50) b_ih:(200) b_hh:(200)
// W_out:(513,50) b_out:(513)  -> out:(64,512,513) fp32

#define B_SZ 64
#define T_SZ 512
#define F_SZ 513
#define H_SZ 50
#define G_SZ 200            // 4*H
#define M_SZ (B_SZ * T_SZ)  // 32768

typedef __attribute__((ext_vector_type(8))) short short8;   // bf16x8 MFMA frag
typedef __attribute__((ext_vector_type(4))) float f32x4;    // MFMA acc
typedef __attribute__((ext_vector_type(2))) float f32x2;    // packed-FMA pair

__device__ __forceinline__ float bf2f(unsigned short u) {
  unsigned int v = ((unsigned int)u) << 16;
  return __builtin_bit_cast(float, v);
}
__device__ __forceinline__ unsigned short f2bf(float f) {
  unsigned int b = __builtin_bit_cast(unsigned int, f);
  unsigned int r = b + 0x7FFFu + ((b >> 16) & 1u);
  return (unsigned short)(r >> 16);
}

// Anti-rematerialization pin (r3/r4): keeps loop-invariant weights resident.
__device__ __forceinline__ void pin2(f32x2& v) {
  double d = __builtin_bit_cast(double, v);
  asm volatile("" : "+v"(d));
  v = __builtin_bit_cast(f32x2, d);
}
__device__ __forceinline__ void pin1(float& v) { asm volatile("" : "+v"(v)); }

// async global->LDS; LDS dest = wave-uniform base + lane*size.
__device__ __forceinline__ void gll16(const void* g, void* l) {
  __builtin_amdgcn_global_load_lds(
      (const __attribute__((address_space(1))) unsigned int*)g,
      (__attribute__((address_space(3))) unsigned int*)l, 16, 0, 0);
}
__device__ __forceinline__ void gll4(const void* g, void* l) {
  __builtin_amdgcn_global_load_lds(
      (const __attribute__((address_space(1))) unsigned int*)g,
      (__attribute__((address_space(3))) unsigned int*)l, 4, 0, 0);
}

// --------------- K0w: weights -> bf16 MFMA fragments (consumption order)
// Wf_ih[(t*13+nt)*64+lane] : n=nt*16+(lane&15), k=t*32+(lane>>4)*8+j, t=0..15
//   (k=512 column handled separately via w512f fp32 rank-1 in gemm_xg)
// Wf_out[(t*33+nt)*64+lane]: n=nt*16+(lane&15), k=t*32+(lane>>4)*8+j, t=0..1
// w512f[n] = Wih[n][512] fp32.
#define NF_IH (16 * 13 * 64)   // 13312 frags
#define NF_OUT (2 * 33 * 64)   // 4224 frags
__global__ __launch_bounds__(256) void conv_weights(
    const float* __restrict__ Wih, const float* __restrict__ Wout,
    unsigned short* __restrict__ Wf_ih, unsigned short* __restrict__ Wf_out,
    float* __restrict__ w512f) {
  int idx = blockIdx.x * 256 + threadIdx.x;
  if (idx < NF_IH) {
    int lane = idx & 63;
    int nt = (idx >> 6) % 13;
    int t = idx / (13 * 64);
    int n = nt * 16 + (lane & 15);
    int k0 = t * 32 + (lane >> 4) * 8;
    short8 v;
#pragma unroll
    for (int j = 0; j < 8; j++) {
      int k = k0 + j;
      v[j] = (n < G_SZ) ? (short)f2bf(Wih[(size_t)n * F_SZ + k]) : (short)0;
    }
    *(short8*)(Wf_ih + (size_t)idx * 8) = v;
  } else if (idx < NF_IH + NF_OUT) {
    int id2 = idx - NF_IH;
    int lane = id2 & 63;
    int nt = (id2 >> 6) % 33;
    int t = id2 / (33 * 64);
    int n = nt * 16 + (lane & 15);
    int k0 = t * 32 + (lane >> 4) * 8;
    short8 v;
#pragma unroll
    for (int j = 0; j < 8; j++) {
      int k = k0 + j;
      v[j] = (n < F_SZ && k < H_SZ) ? (short)f2bf(Wout[(size_t)n * H_SZ + k])
                                    : (short)0;
    }
    *(short8*)(Wf_out + (size_t)id2 * 8) = v;
  } else if (idx < NF_IH + NF_OUT + G_SZ) {
    int n = idx - NF_IH - NF_OUT;
    w512f[n] = Wih[(size_t)n * F_SZ + 512];
  }
}

// ---------------------------------------------------------------- K1: xg GEMM
// xg(32768 x 200, bf16) = x(32768 x 513, fp32, cvt in-register) @ W_ih^T + bih.
// r8 post-mortem: the per-t __syncthreads drained vmcnt(0), exposing ~600cy of
// HBM latency per iteration.  Fix (T3/T4): TRIPLE-buffer, stage(t+2) each
// iteration, counted `s_waitcnt vmcnt(12)` + RAW s_barrier (never drain to 0
// in the loop; peeled t=15 uses vmcnt(0)).  vmcnt counts are made per-wave
// UNIFORM (12 ops/stage): 3 full gll16 rounds + the 1024B Wf tail staged
// redundantly by all 4 waves (same src/dst/data - benign) + 8 gll4 x-rounds.
// k=512 is no longer a staged slab: exact fp32 rank-1 (xtail * w512f) in the
// epilogue.  asm ""::"memory" fences pin stage issue order for the counts.
#define TSLAB 13312  // Wf: 13 frags * 64 lanes * 16B
__global__ __launch_bounds__(256, 2) void gemm_xg_mfma(
    const float* __restrict__ x, const unsigned short* __restrict__ Wf,
    const float* __restrict__ bih, const float* __restrict__ w512,
    unsigned short* __restrict__ xg) {
  int tid = threadIdx.x;
  int wave = tid >> 6;
  int lane = tid & 63;
  int m0 = blockIdx.x * 64 + wave * 16;
  int brow0 = blockIdx.x * 64;
  int arow = lane & 15;  // m within tile
  int kg = lane >> 4;
  __shared__ __align__(16) unsigned short bbuf[3][TSLAB / 2];  // 3 x 13,312 B
  __shared__ __align__(16) float xbuf[3][2048];                // 3 x 8,192 B

  f32x4 acc[13];
#pragma unroll
  for (int nt = 0; nt < 13; nt++) acc[nt] = (f32x4){0.f, 0.f, 0.f, 0.f};

  auto stage = [&](int pb, int t) {  // exactly 12 VMEM ops per wave
    const char* wsrc = (const char*)Wf + (size_t)t * TSLAB;
    char* wdst = (char*)&bbuf[pb][0];
    gll16(wsrc + 0 * 4096 + tid * 16, wdst + 0 * 4096 + wave * 1024);
    gll16(wsrc + 1 * 4096 + tid * 16, wdst + 1 * 4096 + wave * 1024);
    gll16(wsrc + 2 * 4096 + tid * 16, wdst + 2 * 4096 + wave * 1024);
    gll16(wsrc + 12288 + lane * 16, wdst + 12288);  // all 4 waves duplicate
    // x slab t: rows brow0..+63, bytes [t*128, t*128+128) of each row.
    // physical dword p = q*256+tid; row r = p>>5; col c = (p&31)^((r&7)<<2)
    const char* xt =
        (const char*)x + (size_t)brow0 * (F_SZ * 4) + (size_t)t * 128;
    char* xdst = (char*)&xbuf[pb][0];
#pragma unroll
    for (int q = 0; q < 8; q++) {
      int p = q * 256 + tid;
      int r = p >> 5;
      int c4 = (((p & 31) ^ ((r & 7) << 2))) << 2;
      gll4(xt + (size_t)r * (F_SZ * 4) + c4, xdst + q * 1024 + wave * 256);
    }
  };

  // lane's logical x bytes: row*128 + kg*32 (+16), row = wave*16+arow;
  // swizzled physical offset (note (row&7) == (arow&7)); 16B-aligned.
  int xrow = wave * 16 + arow;
  int xb0 = (xrow * 128 + kg * 32) ^ ((xrow & 7) << 4);

  auto computeT = [&](int t) {
    int pb = t % 3;
    const char* xl = (const char*)&xbuf[pb][0];
    f32x4 lo = *(const f32x4*)(xl + xb0);
    f32x4 hi = *(const f32x4*)(xl + (xb0 ^ 16));
    short8 af;
#pragma unroll
    for (int jj = 0; jj < 4; jj++) af[jj] = (short)f2bf(lo[jj]);
#pragma unroll
    for (int jj = 0; jj < 4; jj++) af[4 + jj] = (short)f2bf(hi[jj]);
    const short8* bb = (const short8*)&bbuf[pb][0];
#pragma unroll
    for (int nt = 0; nt < 13; nt++) {
      short8 bf = bb[nt * 64 + lane];
      acc[nt] = __builtin_amdgcn_mfma_f32_16x16x32_bf16(bf, af, acc[nt], 0, 0, 0);
    }
  };

  // prologue: xtail (k=512) + stages 0,1 in flight (order pinned by fences)
  float xtail = x[(size_t)(m0 + arow) * F_SZ + 512];
  asm volatile("" ::: "memory");
  stage(0, 0);
  asm volatile("" ::: "memory");
  stage(1, 1);
  asm volatile("" ::: "memory");

#pragma unroll 1
  for (int t = 0; t < 15; ++t) {
    // wait for stage(t): 12 newer ops (stage t+1) may remain in flight
    asm volatile("s_waitcnt vmcnt(12)" ::: "memory");
    __builtin_amdgcn_s_barrier();  // raw: does NOT drain vmcnt
    asm volatile("" ::: "memory");
    if (t + 2 < 16) stage((t + 2) % 3, t + 2);  // overwrites buf read at t-1
    asm volatile("" ::: "memory");
    computeT(t);
  }
  // peeled t=15: nothing newer in flight -> full drain
  asm volatile("s_waitcnt vmcnt(0)" ::: "memory");
  __builtin_amdgcn_s_barrier();
  asm volatile("" ::: "memory");
  computeT(15);

  // epilogue: bias + exact fp32 rank-1 for k=512
  unsigned short* xrowp = xg + (size_t)(m0 + arow) * G_SZ;
#pragma unroll
  for (int nt = 0; nt < 13; nt++) {
    int nb = nt * 16 + kg * 4;
    if (nt < 12 || kg < 2) {  // n < 200
      float4 bi = *(const float4*)&bih[nb];
      float4 wq = *(const float4*)&w512[nb];
      ushort4 o;
      o.x = f2bf(fmaf(xtail, wq.x, acc[nt][0] + bi.x));
      o.y = f2bf(fmaf(xtail, wq.y, acc[nt][1] + bi.y));
      o.z = f2bf(fmaf(xtail, wq.z, acc[nt][2] + bi.z));
      o.w = f2bf(fmaf(xtail, wq.w, acc[nt][3] + bi.w));
      *(ushort4*)(xrowp + nb) = o;
    }
  }
}

// ------------------------------------------------------------- K2: recurrence
__device__ __forceinline__ float sig_f(float v) {
  return 1.0f / (1.0f + __expf(-v));
}
__device__ __forceinline__ float tanh_f(float v) {
  return 2.0f / (1.0f + __expf(-2.0f * v)) - 1.0f;
}

// r8 structure (47.0us) with ONE change: the per-step __syncthreads (which
// compiles to s_waitcnt vmcnt(0) lgkmcnt(0) + s_barrier and therefore DRAINED
// the 8-step xg prefetch queue every step, exposing HBM latency) is replaced
// by `s_waitcnt lgkmcnt(0)` (LDS-visibility only) + RAW s_barrier.  Global
// prefetch loads now genuinely stay in flight across 8 steps.
__global__ __launch_bounds__(256, 2) void lstm_rec(
    const unsigned short* __restrict__ xg, const float* __restrict__ Whh,
    const float* __restrict__ bhh, unsigned short* __restrict__ hs_b) {
  int t = blockIdx.x;
  int g = threadIdx.x >> 6;   // gate 0..3 (i,f,g,o)
  int j = threadIdx.x & 63;
  int jc = (j < H_SZ) ? j : (H_SZ - 1);
  __shared__ __align__(16) float h_s[4][64];     // per-wave private h copy
  __shared__ __align__(16) float gact[2][4][64]; // double-buffered activations

  int grow = g * H_SZ + jc;
  float bh = bhh[grow];
  pin1(bh);
  f32x2 w2[25];
#pragma unroll
  for (int k = 0; k < 25; k++) {
    w2[k] = *(const f32x2*)(Whh + (size_t)grow * H_SZ + 2 * k);
    pin2(w2[k]);  // non-rematerializable: resident for all 64 steps
  }

  h_s[g][j] = 0.f;
  float c = 0.f;

  const size_t bstr = (size_t)T_SZ * G_SZ;
  const unsigned short* xp = xg + (size_t)t * G_SZ + grow;

  // 8-step-deep prefetch of this wave's gate stream (1 ushort per step)
  unsigned short rA[4], rB[4];
#pragma unroll
  for (int q = 0; q < 4; q++) rA[q] = xp[(size_t)q * bstr];
#pragma unroll
  for (int q = 0; q < 4; q++) rB[q] = xp[(size_t)(4 + q) * bstr];

#pragma unroll 1
  for (int b0 = 0; b0 < B_SZ; b0 += 8) {
    float xf[8];
#pragma unroll
    for (int q = 0; q < 4; q++) xf[q] = bf2f(rA[q]);
    if (b0 + 8 < B_SZ) {
#pragma unroll
      for (int q = 0; q < 4; q++) rA[q] = xp[(size_t)(b0 + 8 + q) * bstr];
    }
#pragma unroll
    for (int q = 0; q < 4; q++) xf[4 + q] = bf2f(rB[q]);
    if (b0 + 12 < B_SZ) {
#pragma unroll
      for (int q = 0; q < 4; q++) rB[q] = xp[(size_t)(b0 + 12 + q) * bstr];
    }

#pragma unroll
    for (int u = 0; u < 8; u++) {  // static u: xf index and gact parity fold
      f32x2 aa = (f32x2){xf[u] + bh, 0.f};
      f32x2 ab = (f32x2){0.f, 0.f};

      // h broadcast: 12 x b128 + 1 x b64, wave-uniform addresses
      const float4* h4 = (const float4*)h_s[g];
#pragma unroll
      for (int kq = 0; kq < 12; kq++) {
        float4 hv = h4[kq];
        aa = __builtin_elementwise_fma((f32x2){hv.x, hv.y}, w2[2 * kq], aa);
        ab = __builtin_elementwise_fma((f32x2){hv.z, hv.w}, w2[2 * kq + 1], ab);
      }
      {
        f32x2 hl = *(const f32x2*)(h_s[g] + 48);
        aa = __builtin_elementwise_fma(hl, w2[24], aa);
      }
      float av = (aa[0] + ab[0]) + (aa[1] + ab[1]);

      gact[u & 1][g][j] = (g == 2) ? tanh_f(av) : sig_f(av);
      // LDS-visibility-only barrier: keep global prefetch (vmcnt) in flight
      asm volatile("s_waitcnt lgkmcnt(0)" ::: "memory");
      __builtin_amdgcn_s_barrier();
      asm volatile("" ::: "memory");

      float iv = gact[u & 1][0][jc];
      float fv = gact[u & 1][1][jc];
      float gv = gact[u & 1][2][jc];
      float ov = gact[u & 1][3][jc];
      c = fmaf(fv, c, iv * gv);
      float h = ov * tanh_f(c);
      float hval = (j < H_SZ) ? h : 0.f;

      h_s[g][j] = hval;  // own copy; in-wave DS ordering only
      if (g == 1)
        hs_b[((size_t)(b0 + u) * T_SZ + t) * 64 + j] = f2bf(hval);
    }
  }
}

// ------------------------------------------------------------ K3: out GEMM
// out(32768 x 513, fp32) = hs_b(32768 x 64, bf16, k-padded) @ Wout^T + b_out.
// Wf_out (67,584 B) staged ONCE into LDS; nt loop reads LDS; write-bound.
__global__ __launch_bounds__(256, 2) void gemm_out_mfma(
    const unsigned short* __restrict__ hs_b,
    const unsigned short* __restrict__ Wf, const float* __restrict__ bout,
    float* __restrict__ out) {
  int tid = threadIdx.x;
  int wave = tid >> 6;
  int lane = tid & 63;
  int m0 = blockIdx.x * 64 + wave * 16;
  int arow = lane & 15;  // m within tile
  int kg = lane >> 4;
  __shared__ __align__(16) unsigned short wbuf[NF_OUT * 8];  // 67,584 B

  {
    const char* src = (const char*)Wf;
    char* dst = (char*)wbuf;
#pragma unroll
    for (int q = 0; q < 16; q++)
      gll16(src + q * 4096 + tid * 16, dst + q * 4096 + wave * 1024);
    if (wave < 2) gll16(src + 65536 + tid * 16, dst + 65536 + wave * 1024);
  }

  const short8* Af = (const short8*)(hs_b + (size_t)(m0 + arow) * 64);
  short8 af0 = Af[kg];      // k = kg*8
  short8 af1 = Af[4 + kg];  // k = 32 + kg*8
  float* orow = out + (size_t)(m0 + arow) * F_SZ;
  __syncthreads();  // drain staging (implicit vmcnt(0)) before LDS reads

  const short8* bb = (const short8*)wbuf;
#pragma unroll
  for (int nt = 0; nt < 33; nt++) {
    short8 bf0 = bb[nt * 64 + lane];
    short8 bf1 = bb[(33 + nt) * 64 + lane];
    f32x4 acc = (f32x4){0.f, 0.f, 0.f, 0.f};
    acc = __builtin_amdgcn_mfma_f32_16x16x32_bf16(bf0, af0, acc, 0, 0, 0);
    acc = __builtin_amdgcn_mfma_f32_16x16x32_bf16(bf1, af1, acc, 0, 0, 0);
    if (nt < 32) {
      int f0 = nt * 16 + kg * 4;
      float4 bv = *(const float4*)&bout[f0];
      float4 o = make_float4(acc[0] + bv.x, acc[1] + bv.y, acc[2] + bv.z,
                             acc[3] + bv.w);
      *(float4*)(orow + f0) = o;  // rows 4B-aligned; HW handles unaligned x4
    } else if (kg == 0) {
      orow[512] = acc[0] + bout[512];  // nt=32: only f=512 real
    }
  }
}

extern "C" void kernel_launch(void* const* d_in, const int* in_sizes, int n_in,
                              void* d_out, int out_size, void* d_ws,
                              size_t ws_size, hipStream_t stream) {
  const float* x = (const float*)d_in[0];
  const float* Wih = (const float*)d_in[1];
  const float* Whh = (const float*)d_in[2];
  const float* bih = (const float*)d_in[3];
  const float* bhh = (const float*)d_in[4];
  const float* Wout = (const float*)d_in[5];
  const float* bout = (const float*)d_in[6];
  float* out = (float*)d_out;

  // ws layout (17.58 MB):
  //   xg_b   : bf16 [32768][200]   13,107,200 B @ 0
  //   hs_b   : bf16 [32768][64]     4,194,304 B @ 13,107,200
  //   Wf_ih  : 16*13*64 frags         212,992 B @ 17,301,504
  //   Wf_out : 2*33*64 frags           67,584 B @ 17,514,496
  //   w512f  : fp32 [200]                 800 B @ 17,582,080
  unsigned short* xg_b = (unsigned short*)d_ws;
  unsigned short* hs_b = (unsigned short*)((char*)d_ws + 13107200);
  unsigned short* Wf_ih = (unsigned short*)((char*)d_ws + 17301504);
  unsigned short* Wf_out = (unsigned short*)((char*)d_ws + 17514496);
  float* w512f = (float*)((char*)d_ws + 17582080);

  conv_weights<<<(NF_IH + NF_OUT + G_SZ + 255) / 256, 256, 0, stream>>>(
      Wih, Wout, Wf_ih, Wf_out, w512f);

  gemm_xg_mfma<<<M_SZ / 64, 256, 0, stream>>>(x, Wf_ih, bih, w512f, xg_b);

  lstm_rec<<<T_SZ, 256, 0, stream>>>(xg_b, Whh, bhh, hs_b);

  gemm_out_mfma<<<M_SZ / 64, 256, 0, stream>>>(hs_b, Wf_out, bout, out);
}